// Round 10
// baseline (78.028 us; speedup 1.0000x reference)
//
#include <hip/hip_runtime.h>

#define B_ 8
#define C_ 256
#define N_ 4096
#define CK 32
#define CG 128
#define M_ 1024

typedef __attribute__((ext_vector_type(8))) short bf16x8;
typedef __attribute__((ext_vector_type(4))) float f32x4;

__device__ __forceinline__ short f2bf(float f) {
  union { float f; unsigned u; } v; v.f = f;
  unsigned r = (v.u + 0x7FFF + ((v.u >> 16) & 1)) >> 16;  // RNE
  return (short)r;
}
__device__ __forceinline__ int cvtpk(float lo, float hi) {
  int r;
  asm("v_cvt_pk_bf16_f32 %0, %1, %2" : "=v"(r) : "v"(lo), "v"(hi));
  return r;
}

// ---------------- fused projection: theta (unpooled) + phi/g (2x2 maxpooled)
// Weights staged directly from f32 (no prep kernel).
__global__ __launch_bounds__(512) void proj_kernel(const float* __restrict__ x,
                                                   const float* __restrict__ wt,
                                                   const float* __restrict__ wp,
                                                   const float* __restrict__ wg,
                                                   short* __restrict__ theta_t,
                                                   short* __restrict__ phi_t,
                                                   short* __restrict__ g_bf) {
  __shared__ __align__(16) short w_s[192 * 256];  // 96 KB, 16B-group swizzle g^(o&7)
  __shared__ __align__(16) short x_s[64 * 256];   // 32 KB, 16B-group swizzle g^(nl&7)
  int tid = threadIdx.x;
  int bx = blockIdx.x, b = blockIdx.y;
  int t = bx >> 1, half = bx & 1;

  // stage W from f32: rows 0..31 theta, 32..63 phi, 64..191 g
#pragma unroll
  for (int rep = 0; rep < 12; ++rep) {
    int idx = rep * 512 + tid;
    int o = idx >> 5, gp = idx & 31;
    const float* src = (o < 32) ? (wt + o * 256)
                     : (o < 64) ? (wp + (o - 32) * 256)
                                : (wg + (o - 64) * 256);
    float4 f0 = *(const float4*)(src + gp * 8);
    float4 f1 = *(const float4*)(src + gp * 8 + 4);
    int4 pk;
    pk.x = cvtpk(f0.x, f0.y); pk.y = cvtpk(f0.z, f0.w);
    pk.z = cvtpk(f1.x, f1.y); pk.w = cvtpk(f1.z, f1.w);
    *(int4*)&w_s[o * 256 + ((gp ^ (o & 7)) * 8)] = pk;
  }
  {
    int l = tid & 63, cq = tid >> 6;
    int xoff = l >> 1, dy = l & 1;
    int n = t * 128 + dy * 64 + half * 32 + xoff;
    const float* xb = x + (size_t)b * C_ * N_ + n;
#pragma unroll
    for (int rep = 0; rep < 2; ++rep) {
      int ch = cq + rep * 8;
      int c0 = ch * 16;
      float f[16];
#pragma unroll
      for (int i = 0; i < 16; ++i) f[i] = xb[(size_t)(c0 + i) * N_];
      int4 pa, pb;
      pa.x = cvtpk(f[0], f[1]);   pa.y = cvtpk(f[2], f[3]);
      pa.z = cvtpk(f[4], f[5]);   pa.w = cvtpk(f[6], f[7]);
      pb.x = cvtpk(f[8], f[9]);   pb.y = cvtpk(f[10], f[11]);
      pb.z = cvtpk(f[12], f[13]); pb.w = cvtpk(f[14], f[15]);
      *(int4*)&x_s[l * 256 + (((2 * ch) ^ (l & 7)) * 8)] = pa;
      *(int4*)&x_s[l * 256 + (((2 * ch + 1) ^ (l & 7)) * 8)] = pb;
    }
  }
  __syncthreads();

  int lane = tid & 63, w = tid >> 6;
  int h = lane >> 4, q = lane & 15;
  int ns = w & 3, ow = w >> 2;
  f32x4 acc[6];
#pragma unroll
  for (int j = 0; j < 6; ++j) acc[j] = (f32x4){0.f, 0.f, 0.f, 0.f};

  int nl = 16 * ns + q;
#pragma unroll
  for (int ks = 0; ks < 8; ++ks) {
    bf16x8 bfr = *(const bf16x8*)&x_s[nl * 256 + (((4 * ks + h) ^ (nl & 7)) * 8)];
#pragma unroll
    for (int j = 0; j < 6; ++j) {
      int o = 16 * (6 * ow + j) + q;
      bf16x8 afr = *(const bf16x8*)&w_s[o * 256 + (((4 * ks + h) ^ (o & 7)) * 8)];
      acc[j] = __builtin_amdgcn_mfma_f32_16x16x32_bf16(afr, bfr, acc[j], 0, 0, 0);
    }
  }

  int xoff = nl >> 1, dy = nl & 1;
  int n = t * 128 + dy * 64 + half * 32 + xoff;
  int m = t * 32 + half * 16 + (nl >> 2);
#pragma unroll
  for (int j = 0; j < 6; ++j) {
    int ot = 6 * ow + j;
    if (ot < 2) {  // theta, unpooled
      int2 pp;
      pp.x = cvtpk(acc[j][0], acc[j][1]);
      pp.y = cvtpk(acc[j][2], acc[j][3]);
      *(int2*)&theta_t[((size_t)b * N_ + n) * CK + ot * 16 + 4 * h] = pp;
    } else {  // pooled
      float v[4];
#pragma unroll
      for (int r = 0; r < 4; ++r) {
        float vv = acc[j][r];
        vv = fmaxf(vv, __shfl_xor(vv, 1));
        vv = fmaxf(vv, __shfl_xor(vv, 2));
        v[r] = vv;
      }
      if ((nl & 3) == 0) {
        if (ot < 4) {  // phi
          int2 pp;
          pp.x = cvtpk(v[0], v[1]);
          pp.y = cvtpk(v[2], v[3]);
          *(int2*)&phi_t[((size_t)b * M_ + m) * CK + (ot - 2) * 16 + 4 * h] = pp;
        } else {  // g
#pragma unroll
          for (int r = 0; r < 4; ++r) {
            int oc = (ot - 4) * 16 + 4 * h + r;
            g_bf[((size_t)b * CG + oc) * M_ + m] = f2bf(v[r]);
          }
        }
      }
    }
  }
}

// ---------------- fused flash-attention + out-projection + residual
// KVBLK=128: 8 m-iterations. phi double-buffered; g single-buffered with
// early-issued loads + write-late after the read barrier (T14).
// LDS strides 40/136 sh give uniform bank spread (min dw/bank) on all b128 ops.
__global__ __launch_bounds__(512, 1) void attn_out_kernel(const short* __restrict__ theta_t,
                                                          const short* __restrict__ phi_t,
                                                          const short* __restrict__ g_bf,
                                                          const float* __restrict__ wo,
                                                          const float* __restrict__ x,
                                                          const float* __restrict__ gamma,
                                                          float* __restrict__ out) {
  __shared__ __align__(16) short lds[50176];  // 100,352 B
  short* phi_s = lds;          // 2 x 5120 sh  ([m 0..127][c] stride 40)
  short* g_s = lds + 10240;    // 17408 sh     ([c 0..127][m 0..127] stride 136)
  short* p_sb = lds + 27648;   // 8 x 2176 sh  (per-wave [q][m 0..127] stride 136)

  int tid = threadIdx.x;
  int lane = tid & 63, w = tid >> 6;
  int h = lane >> 4, q = lane & 15;
  int bid = blockIdx.x;
  int b = bid & 7, n0 = (bid >> 3) * 128;  // same-b blocks land on same XCD
  int n = n0 + 16 * w + q;
  float gm = gamma[0];

  bf16x8 qfrag = *(const bf16x8*)&theta_t[((size_t)b * N_ + n) * CK + 8 * h];

  f32x4 Oacc[8];
#pragma unroll
  for (int ct = 0; ct < 8; ++ct) Oacc[ct] = (f32x4){0.f, 0.f, 0.f, 0.f};
  float Mx = -INFINITY, S = 0.f;
  const f32x4 zero4 = {0.f, 0.f, 0.f, 0.f};

  // staging coords: phi 1 int4/thread (128m x 32c); g 4 int4/thread (128c x 128m)
  int pm_ = tid >> 2, pc_ = tid & 3;
  int gm_ = tid & 15;
  short* p_sw = p_sb + w * 2176;

  // prologue: stage tile 0
  *(int4*)&phi_s[pm_ * 40 + 8 * pc_] =
      *(const int4*)&phi_t[((size_t)b * M_ + pm_) * CK + 8 * pc_];
#pragma unroll
  for (int k = 0; k < 4; ++k) {
    int gc = (k * 512 + tid) >> 4;
    *(int4*)&g_s[gc * 136 + 8 * gm_] =
        *(const int4*)&g_bf[((size_t)b * CG + gc) * M_ + 8 * gm_];
  }
  __syncthreads();

  for (int it = 0; it < 8; ++it) {
    int cur = it & 1;
    const short* phi_c = phi_s + cur * 5120;
    // issue next tile's global loads early (T14)
    int4 rphi, rg[4];
    if (it < 7) {
      int m0n = (it + 1) * 128;
      rphi = *(const int4*)&phi_t[((size_t)b * M_ + m0n + pm_) * CK + 8 * pc_];
#pragma unroll
      for (int k = 0; k < 4; ++k) {
        int gc = (k * 512 + tid) >> 4;
        rg[k] = *(const int4*)&g_bf[((size_t)b * CG + gc) * M_ + m0n + 8 * gm_];
      }
    }

    // QK^T: P^T[m][n] for own 16-n slice, 128 m
    f32x4 pt[8];
#pragma unroll
    for (int mt = 0; mt < 8; ++mt) {
      bf16x8 af = *(const bf16x8*)&phi_c[(16 * mt + q) * 40 + 8 * h];
      pt[mt] = __builtin_amdgcn_mfma_f32_16x16x32_bf16(af, qfrag, zero4, 0, 0, 0);
    }

    // online softmax over 128 m, defer-max THR=8
    float pm = pt[0][0];
#pragma unroll
    for (int mt = 0; mt < 8; ++mt)
#pragma unroll
      for (int r = 0; r < 4; ++r) pm = fmaxf(pm, pt[mt][r]);
    pm = fmaxf(pm, __shfl_xor(pm, 16));
    pm = fmaxf(pm, __shfl_xor(pm, 32));
    if (!__all(pm - Mx <= 8.f)) {
      float Mn = fmaxf(Mx, pm);
      float fsc = __expf(Mx - Mn);
      S *= fsc;
#pragma unroll
      for (int ct = 0; ct < 8; ++ct) Oacc[ct] *= fsc;
      Mx = Mn;
    }
    float ps = 0.f;
#pragma unroll
    for (int mt = 0; mt < 8; ++mt) {
      float e0 = __expf(pt[mt][0] - Mx);
      float e1 = __expf(pt[mt][1] - Mx);
      float e2 = __expf(pt[mt][2] - Mx);
      float e3 = __expf(pt[mt][3] - Mx);
      ps += (e0 + e1) + (e2 + e3);
      int2 pk;
      pk.x = cvtpk(e0, e1);
      pk.y = cvtpk(e2, e3);
      *(int2*)&p_sw[q * 136 + 16 * mt + 4 * h] = pk;
    }
    ps += __shfl_xor(ps, 16);
    ps += __shfl_xor(ps, 32);
    S += ps;

    // PV: O^T[all 128 c][own 16 n] over 128 m
    __builtin_amdgcn_s_setprio(1);
#pragma unroll
    for (int kp = 0; kp < 4; ++kp) {
      bf16x8 pf = *(const bf16x8*)&p_sw[q * 136 + 32 * kp + 8 * h];
#pragma unroll
      for (int ct = 0; ct < 8; ++ct) {
        bf16x8 vf = *(const bf16x8*)&g_s[(16 * ct + q) * 136 + 32 * kp + 8 * h];
        Oacc[ct] = __builtin_amdgcn_mfma_f32_16x16x32_bf16(vf, pf, Oacc[ct], 0, 0, 0);
      }
    }
    __builtin_amdgcn_s_setprio(0);

    __syncthreads();  // all reads of g_s/phi_s[cur] done
    if (it < 7) {
      *(int4*)&phi_s[(cur ^ 1) * 5120 + pm_ * 40 + 8 * pc_] = rphi;
#pragma unroll
      for (int k = 0; k < 4; ++k) {
        int gc = (k * 512 + tid) >> 4;
        *(int4*)&g_s[gc * 136 + 8 * gm_] = rg[k];
      }
      __syncthreads();  // staged tile visible
    }
  }

  // ---- epilogue phase 1: normalized O -> ot_s[128 n][stride 136]; stage wo f32->bf16
  short* ot_s = lds;            // 17408 sh
  short* wo_s = lds + 17408;    // 32768 sh, swizzle g^(o&7)
  float rS = 1.f / S;
  int nloc = 16 * w + q;
#pragma unroll
  for (int ct = 0; ct < 8; ++ct) {
    int2 pp;
    pp.x = cvtpk(Oacc[ct][0] * rS, Oacc[ct][1] * rS);
    pp.y = cvtpk(Oacc[ct][2] * rS, Oacc[ct][3] * rS);
    *(int2*)&ot_s[nloc * 136 + 16 * ct + 4 * h] = pp;
  }
#pragma unroll
  for (int rep = 0; rep < 8; ++rep) {
    int idx = rep * 512 + tid;
    int o = idx >> 4, gp = idx & 15;
    float4 f0 = *(const float4*)(wo + o * 128 + gp * 8);
    float4 f1 = *(const float4*)(wo + o * 128 + gp * 8 + 4);
    int4 pk;
    pk.x = cvtpk(f0.x, f0.y); pk.y = cvtpk(f0.z, f0.w);
    pk.z = cvtpk(f1.x, f1.y); pk.w = cvtpk(f1.z, f1.w);
    *(int4*)&wo_s[o * 128 + ((gp ^ (o & 7)) * 8)] = pk;
  }
  __syncthreads();

  // ---- epilogue phase 2: out = gamma * (w_o @ O) + x
  int nq = w & 3, oh = w >> 2;
  f32x4 acc[8][2];
#pragma unroll
  for (int j = 0; j < 8; ++j)
#pragma unroll
    for (int nn = 0; nn < 2; ++nn) acc[j][nn] = (f32x4){0.f, 0.f, 0.f, 0.f};

#pragma unroll
  for (int ks = 0; ks < 4; ++ks) {
    bf16x8 bfr0 = *(const bf16x8*)&ot_s[(32 * nq + q) * 136 + 32 * ks + 8 * h];
    bf16x8 bfr1 = *(const bf16x8*)&ot_s[(32 * nq + 16 + q) * 136 + 32 * ks + 8 * h];
#pragma unroll
    for (int j = 0; j < 8; ++j) {
      int o = 128 * oh + 16 * j + q;
      bf16x8 afr = *(const bf16x8*)&wo_s[o * 128 + (((4 * ks + h) ^ (o & 7)) * 8)];
      acc[j][0] = __builtin_amdgcn_mfma_f32_16x16x32_bf16(afr, bfr0, acc[j][0], 0, 0, 0);
      acc[j][1] = __builtin_amdgcn_mfma_f32_16x16x32_bf16(afr, bfr1, acc[j][1], 0, 0, 0);
    }
  }

#pragma unroll
  for (int j = 0; j < 8; ++j)
#pragma unroll
    for (int nn = 0; nn < 2; ++nn)
#pragma unroll
      for (int r = 0; r < 4; ++r) {
        int o = 128 * oh + 16 * j + 4 * h + r;
        int nn2 = n0 + 32 * nq + 16 * nn + q;
        size_t idx = ((size_t)b * C_ + o) * N_ + nn2;
        out[idx] = gm * acc[j][nn][r] + x[idx];
      }
}

extern "C" void kernel_launch(void* const* d_in, const int* in_sizes, int n_in,
                              void* d_out, int out_size, void* d_ws, size_t ws_size,
                              hipStream_t stream) {
  const float* x = (const float*)d_in[0];
  const float* wt = (const float*)d_in[1];
  const float* wp = (const float*)d_in[2];
  const float* wg = (const float*)d_in[3];
  const float* wo = (const float*)d_in[4];
  const float* gamma = (const float*)d_in[5];
  float* out = (float*)d_out;

  short* theta_t = (short*)d_ws;                       // 8*4096*32
  short* phi_t = theta_t + (size_t)B_ * N_ * CK;       // 8*1024*32
  short* g_bf = phi_t + (size_t)B_ * M_ * CK;          // 8*128*1024

  proj_kernel<<<dim3(64, 8), 512, 0, stream>>>(x, wt, wp, wg, theta_t, phi_t, g_bf);
  attn_out_kernel<<<dim3(256), 512, 0, stream>>>(theta_t, phi_t, g_bf, wo, x, gamma, out);
}

// Round 11
// 59.304 us; speedup vs baseline: 1.3157x; 1.3157x over previous
//
#include <hip/hip_runtime.h>

#define B_ 8
#define C_ 256
#define N_ 4096
#define CK 32
#define CG 128
#define M_ 1024

typedef __attribute__((ext_vector_type(8))) short bf16x8;
typedef __attribute__((ext_vector_type(4))) float f32x4;

__device__ __forceinline__ short f2bf(float f) {
  union { float f; unsigned u; } v; v.f = f;
  unsigned r = (v.u + 0x7FFF + ((v.u >> 16) & 1)) >> 16;  // RNE
  return (short)r;
}
__device__ __forceinline__ int cvtpk(float lo, float hi) {
  int r;
  asm("v_cvt_pk_bf16_f32 %0, %1, %2" : "=v"(r) : "v"(lo), "v"(hi));
  return r;
}

// ---------------- fused projection: theta (unpooled) + phi/g (2x2 maxpooled)
__global__ __launch_bounds__(512) void proj_kernel(const float* __restrict__ x,
                                                   const float* __restrict__ wt,
                                                   const float* __restrict__ wp,
                                                   const float* __restrict__ wg,
                                                   short* __restrict__ theta_t,
                                                   short* __restrict__ phi_t,
                                                   short* __restrict__ g_bf) {
  __shared__ __align__(16) short w_s[192 * 256];  // 96 KB, 16B-group swizzle g^(o&7)
  __shared__ __align__(16) short x_s[64 * 256];   // 32 KB, 16B-group swizzle g^(nl&7)
  int tid = threadIdx.x;
  int bx = blockIdx.x, b = blockIdx.y;
  int t = bx >> 1, half = bx & 1;

#pragma unroll
  for (int rep = 0; rep < 12; ++rep) {
    int idx = rep * 512 + tid;
    int o = idx >> 5, gp = idx & 31;
    const float* src = (o < 32) ? (wt + o * 256)
                     : (o < 64) ? (wp + (o - 32) * 256)
                                : (wg + (o - 64) * 256);
    float4 f0 = *(const float4*)(src + gp * 8);
    float4 f1 = *(const float4*)(src + gp * 8 + 4);
    int4 pk;
    pk.x = cvtpk(f0.x, f0.y); pk.y = cvtpk(f0.z, f0.w);
    pk.z = cvtpk(f1.x, f1.y); pk.w = cvtpk(f1.z, f1.w);
    *(int4*)&w_s[o * 256 + ((gp ^ (o & 7)) * 8)] = pk;
  }
  {
    int l = tid & 63, cq = tid >> 6;
    int xoff = l >> 1, dy = l & 1;
    int n = t * 128 + dy * 64 + half * 32 + xoff;
    const float* xb = x + (size_t)b * C_ * N_ + n;
#pragma unroll
    for (int rep = 0; rep < 2; ++rep) {
      int ch = cq + rep * 8;
      int c0 = ch * 16;
      float f[16];
#pragma unroll
      for (int i = 0; i < 16; ++i) f[i] = xb[(size_t)(c0 + i) * N_];
      int4 pa, pb;
      pa.x = cvtpk(f[0], f[1]);   pa.y = cvtpk(f[2], f[3]);
      pa.z = cvtpk(f[4], f[5]);   pa.w = cvtpk(f[6], f[7]);
      pb.x = cvtpk(f[8], f[9]);   pb.y = cvtpk(f[10], f[11]);
      pb.z = cvtpk(f[12], f[13]); pb.w = cvtpk(f[14], f[15]);
      *(int4*)&x_s[l * 256 + (((2 * ch) ^ (l & 7)) * 8)] = pa;
      *(int4*)&x_s[l * 256 + (((2 * ch + 1) ^ (l & 7)) * 8)] = pb;
    }
  }
  __syncthreads();

  int lane = tid & 63, w = tid >> 6;
  int h = lane >> 4, q = lane & 15;
  int ns = w & 3, ow = w >> 2;
  f32x4 acc[6];
#pragma unroll
  for (int j = 0; j < 6; ++j) acc[j] = (f32x4){0.f, 0.f, 0.f, 0.f};

  int nl = 16 * ns + q;
#pragma unroll
  for (int ks = 0; ks < 8; ++ks) {
    bf16x8 bfr = *(const bf16x8*)&x_s[nl * 256 + (((4 * ks + h) ^ (nl & 7)) * 8)];
#pragma unroll
    for (int j = 0; j < 6; ++j) {
      int o = 16 * (6 * ow + j) + q;
      bf16x8 afr = *(const bf16x8*)&w_s[o * 256 + (((4 * ks + h) ^ (o & 7)) * 8)];
      acc[j] = __builtin_amdgcn_mfma_f32_16x16x32_bf16(afr, bfr, acc[j], 0, 0, 0);
    }
  }

  int xoff = nl >> 1, dy = nl & 1;
  int n = t * 128 + dy * 64 + half * 32 + xoff;
  int m = t * 32 + half * 16 + (nl >> 2);
#pragma unroll
  for (int j = 0; j < 6; ++j) {
    int ot = 6 * ow + j;
    if (ot < 2) {  // theta, unpooled
      int2 pp;
      pp.x = cvtpk(acc[j][0], acc[j][1]);
      pp.y = cvtpk(acc[j][2], acc[j][3]);
      *(int2*)&theta_t[((size_t)b * N_ + n) * CK + ot * 16 + 4 * h] = pp;
    } else {  // pooled
      float v[4];
#pragma unroll
      for (int r = 0; r < 4; ++r) {
        float vv = acc[j][r];
        vv = fmaxf(vv, __shfl_xor(vv, 1));
        vv = fmaxf(vv, __shfl_xor(vv, 2));
        v[r] = vv;
      }
      if ((nl & 3) == 0) {
        if (ot < 4) {  // phi
          int2 pp;
          pp.x = cvtpk(v[0], v[1]);
          pp.y = cvtpk(v[2], v[3]);
          *(int2*)&phi_t[((size_t)b * M_ + m) * CK + (ot - 2) * 16 + 4 * h] = pp;
        } else {  // g
#pragma unroll
          for (int r = 0; r < 4; ++r) {
            int oc = (ot - 4) * 16 + 4 * h + r;
            g_bf[((size_t)b * CG + oc) * M_ + m] = f2bf(v[r]);
          }
        }
      }
    }
  }
}

// ---------------- fused flash-attention + out-projection + residual
// 512 blocks x 256 threads (4 waves, 64 queries): 2 blocks/CU so independent
// blocks hide each other's barrier/softmax chains. KVBLK=64, double-buffered
// phi+g, ONE barrier per m-iteration (r9-proven schedule).
// LDS 56,320 B main loop; epilogue stages w_o in two 128-row halves to stay
// within the same footprint.
__global__ __launch_bounds__(256, 2) void attn_out_kernel(const short* __restrict__ theta_t,
                                                          const short* __restrict__ phi_t,
                                                          const short* __restrict__ g_bf,
                                                          const float* __restrict__ wo,
                                                          const float* __restrict__ x,
                                                          const float* __restrict__ gamma,
                                                          float* __restrict__ out) {
  __shared__ __align__(16) short lds[28160];  // 56,320 B
  short* phi_s = lds;          // 2 x 2560 sh ([m 0..63][c] stride 40)
  short* g_s = lds + 5120;     // 2 x 9216 sh ([c 0..127][m 0..63] stride 72)
  short* p_sb = lds + 23552;   // 4 x 1152 sh (per-wave [q][m] stride 72)

  int tid = threadIdx.x;
  int lane = tid & 63, w = tid >> 6;
  int h = lane >> 4, q = lane & 15;
  int bid = blockIdx.x;
  int b = bid & 7, n0 = (bid >> 3) * 64;  // same-b blocks share an XCD L2
  int n = n0 + 16 * w + q;
  float gm = gamma[0];

  bf16x8 qfrag = *(const bf16x8*)&theta_t[((size_t)b * N_ + n) * CK + 8 * h];

  f32x4 Oacc[8];
#pragma unroll
  for (int ct = 0; ct < 8; ++ct) Oacc[ct] = (f32x4){0.f, 0.f, 0.f, 0.f};
  float Mx = -INFINITY, S = 0.f;
  const f32x4 zero4 = {0.f, 0.f, 0.f, 0.f};

  // staging coords (256 threads): phi 1 int4/thread, g 4 int4/thread
  int pm_ = tid >> 2, pc_ = tid & 3;
  int gm_ = tid & 7;
  short* p_sw = p_sb + w * 1152;

  // prologue: stage tile 0 into buffer 0
  *(int4*)&phi_s[pm_ * 40 + 8 * pc_] =
      *(const int4*)&phi_t[((size_t)b * M_ + pm_) * CK + 8 * pc_];
#pragma unroll
  for (int k = 0; k < 4; ++k) {
    int gc = (k * 256 + tid) >> 3;
    *(int4*)&g_s[gc * 72 + 8 * gm_] =
        *(const int4*)&g_bf[((size_t)b * CG + gc) * M_ + 8 * gm_];
  }
  __syncthreads();

  for (int it = 0; it < 16; ++it) {
    int cur = it & 1;
    const short* phi_c = phi_s + cur * 2560;
    const short* g_c = g_s + cur * 9216;
    // issue next tile's global loads early (T14)
    int4 rphi, rg[4];
    if (it < 15) {
      int m0n = (it + 1) * 64;
      rphi = *(const int4*)&phi_t[((size_t)b * M_ + m0n + pm_) * CK + 8 * pc_];
#pragma unroll
      for (int k = 0; k < 4; ++k) {
        int gc = (k * 256 + tid) >> 3;
        rg[k] = *(const int4*)&g_bf[((size_t)b * CG + gc) * M_ + m0n + 8 * gm_];
      }
    }

    // QK^T: P^T[m][n], own 16-n slice
    f32x4 pt[4];
#pragma unroll
    for (int mt = 0; mt < 4; ++mt) {
      bf16x8 af = *(const bf16x8*)&phi_c[(16 * mt + q) * 40 + 8 * h];
      pt[mt] = __builtin_amdgcn_mfma_f32_16x16x32_bf16(af, qfrag, zero4, 0, 0, 0);
    }

    // online softmax, defer-max THR=8
    float pm = pt[0][0];
#pragma unroll
    for (int mt = 0; mt < 4; ++mt)
#pragma unroll
      for (int r = 0; r < 4; ++r) pm = fmaxf(pm, pt[mt][r]);
    pm = fmaxf(pm, __shfl_xor(pm, 16));
    pm = fmaxf(pm, __shfl_xor(pm, 32));
    if (!__all(pm - Mx <= 8.f)) {
      float Mn = fmaxf(Mx, pm);
      float fsc = __expf(Mx - Mn);
      S *= fsc;
#pragma unroll
      for (int ct = 0; ct < 8; ++ct) Oacc[ct] *= fsc;
      Mx = Mn;
    }
    float ps = 0.f;
#pragma unroll
    for (int mt = 0; mt < 4; ++mt) {
      float e0 = __expf(pt[mt][0] - Mx);
      float e1 = __expf(pt[mt][1] - Mx);
      float e2 = __expf(pt[mt][2] - Mx);
      float e3 = __expf(pt[mt][3] - Mx);
      ps += (e0 + e1) + (e2 + e3);
      int2 pk;
      pk.x = cvtpk(e0, e1);
      pk.y = cvtpk(e2, e3);
      *(int2*)&p_sw[q * 72 + 16 * mt + 4 * h] = pk;
    }
    ps += __shfl_xor(ps, 16);
    ps += __shfl_xor(ps, 32);
    S += ps;

    // PV: O^T[all 128 c][own 16 n]
    __builtin_amdgcn_s_setprio(1);
#pragma unroll
    for (int kp = 0; kp < 2; ++kp) {
      bf16x8 pf = *(const bf16x8*)&p_sw[q * 72 + 32 * kp + 8 * h];
#pragma unroll
      for (int ct = 0; ct < 8; ++ct) {
        bf16x8 vf = *(const bf16x8*)&g_c[(16 * ct + q) * 72 + 32 * kp + 8 * h];
        Oacc[ct] = __builtin_amdgcn_mfma_f32_16x16x32_bf16(vf, pf, Oacc[ct], 0, 0, 0);
      }
    }
    __builtin_amdgcn_s_setprio(0);

    // write next tile into the spare buffers, then ONE barrier
    if (it < 15) {
      int nxt = cur ^ 1;
      *(int4*)&phi_s[nxt * 2560 + pm_ * 40 + 8 * pc_] = rphi;
#pragma unroll
      for (int k = 0; k < 4; ++k) {
        int gc = (k * 256 + tid) >> 3;
        *(int4*)&g_s[nxt * 9216 + gc * 72 + 8 * gm_] = rg[k];
      }
    }
    __syncthreads();
  }

  // ---- epilogue: O stays in LDS; w_o staged in two 128-row halves
  short* ot_s = lds;           // 64 n x stride 136 = 8704 sh
  short* wo_s = lds + 8704;    // 128 o x 128 c = 16384 sh, swizzle g^(o&7)
  float rS = 1.f / S;
  int nloc = 16 * w + q;
#pragma unroll
  for (int ct = 0; ct < 8; ++ct) {
    int2 pp;
    pp.x = cvtpk(Oacc[ct][0] * rS, Oacc[ct][1] * rS);
    pp.y = cvtpk(Oacc[ct][2] * rS, Oacc[ct][3] * rS);
    *(int2*)&ot_s[nloc * 136 + 16 * ct + 4 * h] = pp;
  }

#pragma unroll
  for (int ho = 0; ho < 2; ++ho) {
    // stage w_o rows [128*ho, 128*ho+128) from f32
#pragma unroll
    for (int rep = 0; rep < 8; ++rep) {
      int idx = rep * 256 + tid;
      int ol = idx >> 4, gp = idx & 15;
      const float* src = wo + (size_t)(128 * ho + ol) * 128 + gp * 8;
      float4 f0 = *(const float4*)src;
      float4 f1 = *(const float4*)(src + 4);
      int4 pk;
      pk.x = cvtpk(f0.x, f0.y); pk.y = cvtpk(f0.z, f0.w);
      pk.z = cvtpk(f1.x, f1.y); pk.w = cvtpk(f1.z, f1.w);
      *(int4*)&wo_s[ol * 128 + ((gp ^ (ol & 7)) * 8)] = pk;
    }
    __syncthreads();

    // wave w: o-slice [32w, 32w+32), all 64 n
    f32x4 acc[2][4];
#pragma unroll
    for (int j = 0; j < 2; ++j)
#pragma unroll
      for (int nt = 0; nt < 4; ++nt) acc[j][nt] = (f32x4){0.f, 0.f, 0.f, 0.f};

#pragma unroll
    for (int ks = 0; ks < 4; ++ks) {
      bf16x8 bfr[4];
#pragma unroll
      for (int nt = 0; nt < 4; ++nt)
        bfr[nt] = *(const bf16x8*)&ot_s[(16 * nt + q) * 136 + 32 * ks + 8 * h];
#pragma unroll
      for (int j = 0; j < 2; ++j) {
        int ol = 32 * w + 16 * j + q;
        bf16x8 afr = *(const bf16x8*)&wo_s[ol * 128 + (((4 * ks + h) ^ (ol & 7)) * 8)];
#pragma unroll
        for (int nt = 0; nt < 4; ++nt)
          acc[j][nt] = __builtin_amdgcn_mfma_f32_16x16x32_bf16(afr, bfr[nt], acc[j][nt], 0, 0, 0);
      }
    }

#pragma unroll
    for (int j = 0; j < 2; ++j)
#pragma unroll
      for (int nt = 0; nt < 4; ++nt)
#pragma unroll
        for (int r = 0; r < 4; ++r) {
          int o = 128 * ho + 32 * w + 16 * j + 4 * h + r;
          int nn = n0 + 16 * nt + q;
          size_t idx = ((size_t)b * C_ + o) * N_ + nn;
          out[idx] = gm * acc[j][nt][r] + x[idx];
        }
    if (ho == 0) __syncthreads();  // wo_s reads done before restage
  }
}

extern "C" void kernel_launch(void* const* d_in, const int* in_sizes, int n_in,
                              void* d_out, int out_size, void* d_ws, size_t ws_size,
                              hipStream_t stream) {
  const float* x = (const float*)d_in[0];
  const float* wt = (const float*)d_in[1];
  const float* wp = (const float*)d_in[2];
  const float* wg = (const float*)d_in[3];
  const float* wo = (const float*)d_in[4];
  const float* gamma = (const float*)d_in[5];
  float* out = (float*)d_out;

  short* theta_t = (short*)d_ws;                       // 8*4096*32
  short* phi_t = theta_t + (size_t)B_ * N_ * CK;       // 8*1024*32
  short* g_bf = phi_t + (size_t)B_ * M_ * CK;          // 8*128*1024

  proj_kernel<<<dim3(64, 8), 512, 0, stream>>>(x, wt, wp, wg, theta_t, phi_t, g_bf);
  attn_out_kernel<<<dim3(512), 256, 0, stream>>>(theta_t, phi_t, g_bf, wo, x, gamma, out);
}